// Round 1
// 581.198 us; speedup vs baseline: 1.3855x; 1.3855x over previous
//
#include <hip/hip_runtime.h>
#include <math.h>

// Problem constants (fixed by reference)
constexpr int nB = 8;
constexpr int nC = 512;
constexpr int nH = 96;
constexpr int nW = 96;
constexpr int nP = nH * nW;        // 9216 pixels per batch
constexpr int nCQK = 64;           // q/k channels
constexpr int nS = nH + nW;        // 192 softmax width
constexpr int nO = 640;            // fused q(64)|k(64)|v(512)
constexpr int nM = nB * nP;        // 73728 total pixels

using short8  = __attribute__((ext_vector_type(8))) short;
using ushort8 = __attribute__((ext_vector_type(8))) unsigned short;
using floatx4 = __attribute__((ext_vector_type(4))) float;

__device__ inline unsigned pack_bf16(float a, float b) {
    unsigned ua = __float_as_uint(a), ub = __float_as_uint(b);
    ua = (ua + 0x7fff + ((ua >> 16) & 1)) >> 16;   // RNE
    ub = (ub + 0x7fff + ((ub >> 16) & 1)) >> 16;
    return ua | (ub << 16);
}
__device__ inline ushort f2bf(float a) {
    unsigned ua = __float_as_uint(a);
    return (ushort)((ua + 0x7fff + ((ua >> 16) & 1)) >> 16);
}
__device__ inline float bf2f(ushort u) {
    return __uint_as_float((unsigned)u << 16);
}

// ---------------------------------------------------------------------------
// T1: x[b][c][p] fp32  ->  xT[b*nP+p][c] bf16   (64c x 64p LDS tile)
// ---------------------------------------------------------------------------
__global__ __launch_bounds__(256) void transpose_kernel(
    const float* __restrict__ x, ushort* __restrict__ xT)
{
    __shared__ float T[64 * 65];
    const int b = blockIdx.z, p0 = blockIdx.x * 64, c0 = blockIdx.y * 64;
    const int tid = threadIdx.x;
    #pragma unroll
    for (int it = 0; it < 4; ++it) {
        int c  = it * 16 + (tid >> 4);
        int p4 = (tid & 15) * 4;
        float4 v = *(const float4*)&x[((size_t)b * nC + c0 + c) * nP + p0 + p4];
        T[c * 65 + p4 + 0] = v.x; T[c * 65 + p4 + 1] = v.y;
        T[c * 65 + p4 + 2] = v.z; T[c * 65 + p4 + 3] = v.w;
    }
    __syncthreads();
    #pragma unroll
    for (int it = 0; it < 8; ++it) {
        int idx = it * 256 + tid;
        int p = idx >> 5;              // 0..63
        int c = (idx & 31) * 2;        // even c
        unsigned u = pack_bf16(T[c * 65 + p], T[(c + 1) * 65 + p]);
        *(unsigned*)&xT[((size_t)b * nP + p0 + p) * nC + c0 + c] = u;
    }
}

// ---------------------------------------------------------------------------
// T2: weights -> bf16 Wc[640][512], bias -> bc[640]. One block per o-row.
// ---------------------------------------------------------------------------
__global__ __launch_bounds__(256) void wconv_kernel(
    const float* __restrict__ Wq, const float* __restrict__ bq,
    const float* __restrict__ Wk, const float* __restrict__ bk,
    const float* __restrict__ Wv, const float* __restrict__ bv,
    ushort* __restrict__ Wc, float* __restrict__ bc)
{
    const int o = blockIdx.x, t = threadIdx.x;
    const float *src, *bsrc; int oo;
    if (o < 64)       { src = Wq; bsrc = bq; oo = o; }
    else if (o < 128) { src = Wk; bsrc = bk; oo = o - 64; }
    else              { src = Wv; bsrc = bv; oo = o - 128; }
    float2 v = *(const float2*)&src[(size_t)oo * nC + t * 2];
    *(unsigned*)&Wc[(size_t)o * nC + t * 2] = pack_bf16(v.x, v.y);
    if (t == 0) bc[o] = bsrc[oo];
}

// ---------------------------------------------------------------------------
// G: fused QKV projection via MFMA.
// blockIdx.y==0: qk[m][o(0..127)] fp32 (normal orientation, for score kernels)
// blockIdx.y>=1: v part with SWAPPED operands -> D[c][m] -> writes
//                vW[b][c][h][w] bf16 coalesced in pixel (NCHW).
// ---------------------------------------------------------------------------
__global__ __launch_bounds__(256) void mfma_proj_kernel(
    const ushort* __restrict__ xT, const ushort* __restrict__ Wc,
    const float* __restrict__ bc, float* __restrict__ qk,
    ushort* __restrict__ vW)
{
    __shared__ ushort As[128 * 40];
    __shared__ ushort Bs[128 * 40];
    const int tid = threadIdx.x;
    const int m0 = blockIdx.x * 128;
    const int o0 = blockIdx.y * 128;

    const int sm  = tid >> 2;          // 0..63
    const int skp = tid & 3;           // 0..3
    const ushort* pa0 = xT + (size_t)(m0 + sm) * nC + skp * 8;
    const ushort* pa1 = xT + (size_t)(m0 + sm + 64) * nC + skp * 8;
    const ushort* pb0 = Wc + (size_t)(o0 + sm) * nC + skp * 8;
    const ushort* pb1 = Wc + (size_t)(o0 + sm + 64) * nC + skp * 8;
    ushort* la0 = &As[sm * 40 + skp * 8];
    ushort* la1 = &As[(sm + 64) * 40 + skp * 8];
    ushort* lb0 = &Bs[sm * 40 + skp * 8];
    ushort* lb1 = &Bs[(sm + 64) * 40 + skp * 8];

    const int lane = tid & 63;
    const int wave = tid >> 6;
    const int wr = wave & 1, wc = wave >> 1;
    const int lm = lane & 15, q = lane >> 4;
    int aoff[4], boff[4];
    #pragma unroll
    for (int i = 0; i < 4; ++i) aoff[i] = (wr * 64 + i * 16 + lm) * 40 + q * 8;
    #pragma unroll
    for (int j = 0; j < 4; ++j) boff[j] = (wc * 64 + j * 16 + lm) * 40 + q * 8;

    floatx4 acc[4][4];
    #pragma unroll
    for (int i = 0; i < 4; ++i)
        #pragma unroll
        for (int j = 0; j < 4; ++j) acc[i][j] = (floatx4){0.f, 0.f, 0.f, 0.f};

    const bool vmode = (o0 != 0);

    for (int k0 = 0; k0 < nC; k0 += 32) {
        uint4 a0 = *(const uint4*)(pa0 + k0);
        uint4 a1 = *(const uint4*)(pa1 + k0);
        uint4 b0 = *(const uint4*)(pb0 + k0);
        uint4 b1 = *(const uint4*)(pb1 + k0);
        if (k0) __syncthreads();
        *(uint4*)la0 = a0; *(uint4*)la1 = a1;
        *(uint4*)lb0 = b0; *(uint4*)lb1 = b1;
        __syncthreads();
        short8 av[4], bvv[4];
        #pragma unroll
        for (int i = 0; i < 4; ++i) av[i] = *(const short8*)&As[aoff[i]];
        #pragma unroll
        for (int j = 0; j < 4; ++j) bvv[j] = *(const short8*)&Bs[boff[j]];
        if (!vmode) {
            #pragma unroll
            for (int i = 0; i < 4; ++i)
                #pragma unroll
                for (int j = 0; j < 4; ++j)
                    acc[i][j] = __builtin_amdgcn_mfma_f32_16x16x32_bf16(
                        av[i], bvv[j], acc[i][j], 0, 0, 0);
        } else {
            // swapped: D rows = Wc-row (o/c), D cols = xT-row (m)
            #pragma unroll
            for (int i = 0; i < 4; ++i)
                #pragma unroll
                for (int j = 0; j < 4; ++j)
                    acc[i][j] = __builtin_amdgcn_mfma_f32_16x16x32_bf16(
                        bvv[i], av[j], acc[i][j], 0, 0, 0);
        }
    }

    if (!vmode) {
        // D: col(lm)=o, row(q*4+r)=m
        float bj[4];
        #pragma unroll
        for (int j = 0; j < 4; ++j) bj[j] = bc[wc * 64 + j * 16 + lm];
        #pragma unroll
        for (int i = 0; i < 4; ++i) {
            #pragma unroll
            for (int r = 0; r < 4; ++r) {
                int mrow = m0 + wr * 64 + i * 16 + q * 4 + r;
                float* orow = qk + (size_t)mrow * 128 + wc * 64 + lm;
                #pragma unroll
                for (int j = 0; j < 4; ++j) orow[j * 16] = acc[i][j][r] + bj[j];
            }
        }
    } else {
        // D: row(q*4+r)=o (c), col(lm)=m (pixel)
        const int b  = m0 / nP;
        const int p0 = m0 - b * nP;
        #pragma unroll
        for (int i = 0; i < 4; ++i) {
            #pragma unroll
            for (int r = 0; r < 4; ++r) {
                int o = o0 + wc * 64 + i * 16 + q * 4 + r;
                float bias = bc[o];
                int c = o - 128;
                ushort* vrow = vW + ((size_t)(b * nC + c)) * nP + p0 + wr * 64 + lm;
                #pragma unroll
                for (int j = 0; j < 4; ++j)
                    vrow[j * 16] = f2bf(acc[i][j][r] + bias);
            }
        }
    }
}

// ---------------------------------------------------------------------------
// vtrans: vW[b][c][h][w] -> vH[b][c][w][h]  (bf16 96x96 spatial transpose)
// XOR-swizzled 16-chunk rows so the column gather is bank-conflict-free.
// ---------------------------------------------------------------------------
__global__ __launch_bounds__(256) void vtrans_kernel(
    const ushort* __restrict__ vW, ushort* __restrict__ vH)
{
    __shared__ ushort T[96 * 128];
    const int c = blockIdx.x, b = blockIdx.y, tid = threadIdx.x;
    const size_t base = ((size_t)(b * nC + c)) * nP;
    for (int l = tid; l < 96 * 12; l += 256) {
        int hh = l / 12, seg = l % 12;
        uint4 u = *(const uint4*)&vW[base + (size_t)hh * nW + seg * 8];
        *(uint4*)&T[hh * 128 + ((seg ^ ((hh >> 3) & 7)) * 8)] = u;
    }
    __syncthreads();
    for (int l = tid; l < 96 * 12; l += 256) {
        int ww = l / 12, seg = l % 12;
        ushort8 vv;
        #pragma unroll
        for (int e = 0; e < 8; ++e) {
            int hh = seg * 8 + e;
            int phys = (((ww >> 3) ^ ((hh >> 3) & 7)) * 8) + (ww & 7);
            vv[e] = T[hh * 128 + phys];
        }
        *(ushort8*)&vH[base + (size_t)ww * nH + seg * 8] = vv;
    }
}

// ---------------------------------------------------------------------------
// scores: mode 0 (H): per (b,w) -> eH[h][g], diag=-inf ; mode 1 (W): per (b,h)
// q/k read from qk[m][128] fp32 (offsets 0 / 64).
// ---------------------------------------------------------------------------
__global__ __launch_bounds__(256) void score_kernel(
    const float* __restrict__ qk, float* __restrict__ att, int mode)
{
    __shared__ float Qs[96][68];
    __shared__ float Ks[96][68];
    const int b   = blockIdx.y;
    const int fix = blockIdx.x;
    const int tid = threadIdx.x;

    for (int l = tid; l < 96 * 16; l += 256) {
        int r  = l / 16;
        int c4 = (l % 16) * 4;
        size_t p = (mode == 0) ? ((size_t)r * nW + fix) : ((size_t)fix * nW + r);
        const float* row = &qk[((size_t)b * nP + p) * 128];
        *(float4*)&Qs[r][c4] = *(const float4*)&row[c4];
        *(float4*)&Ks[r][c4] = *(const float4*)&row[64 + c4];
    }
    __syncthreads();

    const int tx = tid % 16;
    const int ty = tid / 16;
    float acc[6][6] = {};
    for (int c4 = 0; c4 < nCQK; c4 += 4) {
        float4 qv[6], kv[6];
        #pragma unroll
        for (int i = 0; i < 6; ++i) qv[i] = *(const float4*)&Qs[ty + 16 * i][c4];
        #pragma unroll
        for (int j = 0; j < 6; ++j) kv[j] = *(const float4*)&Ks[tx + 16 * j][c4];
        #pragma unroll
        for (int i = 0; i < 6; ++i)
            #pragma unroll
            for (int j = 0; j < 6; ++j)
                acc[i][j] += qv[i].x * kv[j].x + qv[i].y * kv[j].y
                           + qv[i].z * kv[j].z + qv[i].w * kv[j].w;
    }

    #pragma unroll
    for (int i = 0; i < 6; ++i) {
        int row = ty + 16 * i;
        #pragma unroll
        for (int j = 0; j < 6; ++j) {
            int col = tx + 16 * j;
            float val = acc[i][j];
            if (mode == 0) {
                if (col == row) val = -INFINITY;
                att[((size_t)b * nP + row * nW + fix) * nS + col] = val;
            } else {
                att[((size_t)b * nP + fix * nW + row) * nS + 96 + col] = val;
            }
        }
    }
}

// ---------------------------------------------------------------------------
// softmax over 192 entries per pixel; fp32 in, bf16 out. One wave per pixel.
// ---------------------------------------------------------------------------
__global__ __launch_bounds__(256) void softmax_kernel(
    const float* __restrict__ att, ushort* __restrict__ attb)
{
    const int wav  = threadIdx.x / 64;
    const int lane = threadIdx.x % 64;
    const size_t pix = (size_t)blockIdx.x * 4 + wav;
    const float* a = att + pix * nS;
    ushort* ab = attb + pix * nS;
    float v0 = a[lane], v1 = a[lane + 64], v2 = a[lane + 128];
    float m = fmaxf(fmaxf(v0, v1), v2);
    #pragma unroll
    for (int off = 32; off; off >>= 1) m = fmaxf(m, __shfl_xor(m, off));
    float e0 = __expf(v0 - m), e1 = __expf(v1 - m), e2 = __expf(v2 - m);
    float s = e0 + e1 + e2;
    #pragma unroll
    for (int off = 32; off; off >>= 1) s += __shfl_xor(s, off);
    float inv = 1.0f / s;
    ab[lane]       = f2bf(e0 * inv);
    ab[lane + 64]  = f2bf(e1 * inv);
    ab[lane + 128] = f2bf(e2 * inv);
}

// ---------------------------------------------------------------------------
// aggH (MFMA): per (b,w): OH[h][c] = sum_g AH[h][g] * vH[c][g]
//   A = attb rows (H half, g-contig); B = vH rows (g-contig).
//   D rows=h, cols=c -> oh[b,p(h,w)][c] bf16, c-coalesced stores.
// ---------------------------------------------------------------------------
__global__ __launch_bounds__(256) void aggH_kernel(
    const ushort* __restrict__ attb, const ushort* __restrict__ vH,
    ushort* __restrict__ oh)
{
    __shared__ ushort As[96 * 104];    // AH[h][g]
    __shared__ ushort Bs[128 * 104];   // vH c-tile [c][g]
    const int b = blockIdx.y, w = blockIdx.x, tid = threadIdx.x;

    for (int l = tid; l < 96 * 12; l += 256) {
        int h = l / 12, seg = l % 12;
        uint4 u = *(const uint4*)&attb[((size_t)(b * nP + h * nW + w)) * nS + seg * 8];
        *(uint4*)&As[h * 104 + seg * 8] = u;
    }
    const int lane = tid & 63, wave = tid >> 6;
    const int wr = wave & 1, wc = wave >> 1;
    const int lm = lane & 15, q = lane >> 4;
    int aoff[3], boff[4];
    #pragma unroll
    for (int i = 0; i < 3; ++i) aoff[i] = (wr * 48 + i * 16 + lm) * 104 + q * 8;
    #pragma unroll
    for (int j = 0; j < 4; ++j) boff[j] = (wc * 64 + j * 16 + lm) * 104 + q * 8;

    for (int ct = 0; ct < 4; ++ct) {
        if (ct) __syncthreads();
        for (int l = tid; l < 128 * 12; l += 256) {
            int cl = l / 12, seg = l % 12;
            uint4 u = *(const uint4*)&vH[((size_t)(b * nC + ct * 128 + cl)) * nP
                                         + w * nH + seg * 8];
            *(uint4*)&Bs[cl * 104 + seg * 8] = u;
        }
        __syncthreads();
        floatx4 acc[3][4];
        #pragma unroll
        for (int i = 0; i < 3; ++i)
            #pragma unroll
            for (int j = 0; j < 4; ++j) acc[i][j] = (floatx4){0.f, 0.f, 0.f, 0.f};
        #pragma unroll
        for (int ks = 0; ks < 3; ++ks) {
            short8 av[3], bvv[4];
            #pragma unroll
            for (int i = 0; i < 3; ++i) av[i] = *(const short8*)&As[aoff[i] + ks * 32];
            #pragma unroll
            for (int j = 0; j < 4; ++j) bvv[j] = *(const short8*)&Bs[boff[j] + ks * 32];
            #pragma unroll
            for (int i = 0; i < 3; ++i)
                #pragma unroll
                for (int j = 0; j < 4; ++j)
                    acc[i][j] = __builtin_amdgcn_mfma_f32_16x16x32_bf16(
                        av[i], bvv[j], acc[i][j], 0, 0, 0);
        }
        #pragma unroll
        for (int i = 0; i < 3; ++i) {
            #pragma unroll
            for (int r = 0; r < 4; ++r) {
                int h = wr * 48 + i * 16 + q * 4 + r;
                ushort* orow = oh + ((size_t)(b * nP + h * nW + w)) * nC
                               + ct * 128 + wc * 64 + lm;
                #pragma unroll
                for (int j = 0; j < 4; ++j) orow[j * 16] = f2bf(acc[i][j][r]);
            }
        }
    }
}

// ---------------------------------------------------------------------------
// aggW (MFMA) + epilogue: per (b,h): OW[w][c] = sum_u AW[w][u] * vW[c][u]
//   swapped operands -> D rows=c, cols=w; out NCHW is w-coalesced.
//   oh tile staged via LDS (layout bridge [p][c] -> [c][w]).
//   out = gamma*(OW + OH) + x.
// ---------------------------------------------------------------------------
__global__ __launch_bounds__(256) void aggW_kernel(
    const ushort* __restrict__ attb, const ushort* __restrict__ vW,
    const ushort* __restrict__ oh, const float* __restrict__ x,
    const float* __restrict__ gamma, float* __restrict__ out)
{
    __shared__ ushort As[96 * 104];    // AW[w][u]
    __shared__ ushort Bs[64 * 104];    // vW c-tile [c][u]
    __shared__ ushort Os[96 * 72];     // oh tile [w][cl]
    const int b = blockIdx.y, h = blockIdx.x, tid = threadIdx.x;
    const float gm = gamma[0];

    for (int l = tid; l < 96 * 12; l += 256) {
        int ww = l / 12, seg = l % 12;
        uint4 u = *(const uint4*)&attb[((size_t)(b * nP + h * nW + ww)) * nS
                                       + 96 + seg * 8];
        *(uint4*)&As[ww * 104 + seg * 8] = u;
    }
    const int lane = tid & 63, wave = tid >> 6;
    const int wr = wave & 1, wc = wave >> 1;   // wr: w-half, wc: c-half
    const int lm = lane & 15, q = lane >> 4;
    int coff[2], woff[3];
    #pragma unroll
    for (int i = 0; i < 2; ++i) coff[i] = (wc * 32 + i * 16 + lm) * 104 + q * 8;
    #pragma unroll
    for (int j = 0; j < 3; ++j) woff[j] = (wr * 48 + j * 16 + lm) * 104 + q * 8;

    for (int ct = 0; ct < 8; ++ct) {
        if (ct) __syncthreads();
        for (int l = tid; l < 64 * 12; l += 256) {
            int cl = l / 12, seg = l % 12;
            uint4 u = *(const uint4*)&vW[((size_t)(b * nC + ct * 64 + cl)) * nP
                                         + h * nW + seg * 8];
            *(uint4*)&Bs[cl * 104 + seg * 8] = u;
        }
        for (int l = tid; l < 96 * 8; l += 256) {
            int ww = l / 8, seg = l % 8;
            uint4 u = *(const uint4*)&oh[((size_t)(b * nP + h * nW + ww)) * nC
                                         + ct * 64 + seg * 8];
            *(uint4*)&Os[ww * 72 + seg * 8] = u;
        }
        __syncthreads();
        floatx4 acc[2][3];
        #pragma unroll
        for (int i = 0; i < 2; ++i)
            #pragma unroll
            for (int j = 0; j < 3; ++j) acc[i][j] = (floatx4){0.f, 0.f, 0.f, 0.f};
        #pragma unroll
        for (int ks = 0; ks < 3; ++ks) {
            short8 cv[2], wv[3];
            #pragma unroll
            for (int i = 0; i < 2; ++i) cv[i] = *(const short8*)&Bs[coff[i] + ks * 32];
            #pragma unroll
            for (int j = 0; j < 3; ++j) wv[j] = *(const short8*)&As[woff[j] + ks * 32];
            #pragma unroll
            for (int i = 0; i < 2; ++i)
                #pragma unroll
                for (int j = 0; j < 3; ++j)
                    acc[i][j] = __builtin_amdgcn_mfma_f32_16x16x32_bf16(
                        cv[i], wv[j], acc[i][j], 0, 0, 0);
        }
        // D: row(q*4+r)=c, col(lm)=w
        #pragma unroll
        for (int i = 0; i < 2; ++i) {
            #pragma unroll
            for (int r = 0; r < 4; ++r) {
                int cl = wc * 32 + i * 16 + q * 4 + r;
                int c  = ct * 64 + cl;
                #pragma unroll
                for (int j = 0; j < 3; ++j) {
                    int ww = wr * 48 + j * 16 + lm;
                    size_t oidx = ((size_t)(b * nC + c) * nH + h) * nW + ww;
                    float ohv = bf2f(Os[ww * 72 + cl]);
                    out[oidx] = gm * (acc[i][j][r] + ohv) + x[oidx];
                }
            }
        }
    }
}

// ---------------------------------------------------------------------------
extern "C" void kernel_launch(void* const* d_in, const int* in_sizes, int n_in,
                              void* d_out, int out_size, void* d_ws, size_t ws_size,
                              hipStream_t stream)
{
    const float* x     = (const float*)d_in[0];
    const float* Wq    = (const float*)d_in[1];
    const float* bq    = (const float*)d_in[2];
    const float* Wk    = (const float*)d_in[3];
    const float* bk    = (const float*)d_in[4];
    const float* Wv    = (const float*)d_in[5];
    const float* bv    = (const float*)d_in[6];
    const float* gamma = (const float*)d_in[7];
    float* out = (float*)d_out;

    // Workspace layout (349.2 MB, fits prior 396.4 MB footprint):
    //  R1 [nM*nC bf16 = 75.5MB]: xT until proj done, then vH (vtrans output)
    //  R2 [nM*128 f32 = 37.7MB]: qk
    //  R3 [nM*nC bf16 = 75.5MB]: vW
    //  R4 [nM*nS f32  = 56.6MB]: Wc+bc (bf16 weights) until scores, then att
    //  R5 [nM*nS bf16 = 28.3MB]: attb
    //  R6 [nM*nC bf16 = 75.5MB]: oh
    char* p = (char*)d_ws;
    ushort* xT  = (ushort*)p;
    ushort* vH  = (ushort*)p;
    p += (size_t)nM * nC * 2;
    float* qk   = (float*)p;
    p += (size_t)nM * 128 * 4;
    ushort* vW  = (ushort*)p;
    p += (size_t)nM * nC * 2;
    float* att  = (float*)p;
    ushort* Wc  = (ushort*)p;
    float* bc   = (float*)(p + (size_t)nO * nC * 2);
    p += (size_t)nM * nS * 4;
    ushort* attb = (ushort*)p;
    p += (size_t)nM * nS * 2;
    ushort* oh  = (ushort*)p;

    dim3 blk(256);
    transpose_kernel<<<dim3(nP / 64, nC / 64, nB), blk, 0, stream>>>(x, xT);
    wconv_kernel<<<dim3(nO), blk, 0, stream>>>(Wq, bq, Wk, bk, Wv, bv, Wc, bc);
    mfma_proj_kernel<<<dim3(nM / 128, nO / 128), blk, 0, stream>>>(xT, Wc, bc, qk, vW);
    vtrans_kernel<<<dim3(nC, nB), blk, 0, stream>>>(vW, vH);
    score_kernel<<<dim3(nW, nB), blk, 0, stream>>>(qk, att, 0);
    score_kernel<<<dim3(nH, nB), blk, 0, stream>>>(qk, att, 1);
    softmax_kernel<<<dim3(nB * nP / 4), blk, 0, stream>>>(att, attb);
    aggH_kernel<<<dim3(nW, nB), blk, 0, stream>>>(attb, vH, oh);
    aggW_kernel<<<dim3(nH, nB), blk, 0, stream>>>(attb, vW, oh, x, gamma, out);
}